// Round 1
// baseline (3695.937 us; speedup 1.0000x reference)
//
#include <hip/hip_runtime.h>
#include <hip/hip_bf16.h>

#define D 128

// ---------------- degree kernels (dst-only, computed once) ----------------
__global__ void deg_count_kernel(const int* __restrict__ dst, int* __restrict__ deg,
                                 int E_) {
    int e = blockIdx.x * blockDim.x + threadIdx.x;
    if (e < E_) atomicAdd(&deg[dst[e]], 1);
}

__global__ void inv_deg_kernel(const int* __restrict__ deg, float* __restrict__ inv_deg,
                               int N_) {
    int n = blockIdx.x * blockDim.x + threadIdx.x;
    if (n < N_) {
        int d = deg[n];
        inv_deg[n] = 1.0f / (float)(d > 0 ? d : 1);
    }
}

// ---------------- scatter-mean numerator: agg[dst] += h[src] ----------------
// one thread per (edge, 4-float chunk): 32 chunks cover D=128.
__global__ __launch_bounds__(256) void scatter_kernel(const float* __restrict__ h,
                                                      const int* __restrict__ src,
                                                      const int* __restrict__ dst,
                                                      float* __restrict__ agg, int E_) {
    int tid = blockIdx.x * blockDim.x + threadIdx.x;
    int e = tid >> 5;
    int c = tid & 31;
    if (e >= E_) return;
    int s = src[e];
    int d = dst[e];
    float4 v = reinterpret_cast<const float4*>(h + (size_t)s * D)[c];
    float* out = agg + (size_t)d * D + (size_t)c * 4;
    atomicAdd(out + 0, v.x);
    atomicAdd(out + 1, v.y);
    atomicAdd(out + 2, v.z);
    atomicAdd(out + 3, v.w);
}

// ---------------- fused layer GEMM: out = (agg*inv_deg)@Wl + b + hin@Wr ----
// BM=32 rows per block, all 128 cols, K tiled by 16. 256 threads:
// col = tid&127, half = tid>>7 (wave-uniform), each thread owns 16 rows.
__global__ __launch_bounds__(256) void sage_layer_gemm(
    const float* __restrict__ hin, const float* __restrict__ agg,
    const float* __restrict__ inv_deg, const float* __restrict__ Wl,
    const float* __restrict__ Wr, const float* __restrict__ bias,
    float* __restrict__ out, int N_, int do_relu) {
    __shared__ float sW[2][16][D];  // Wl chunk, Wr chunk
    __shared__ float sH[32][17];    // +1 pad
    __shared__ float sA[32][17];

    const int tid = threadIdx.x;
    const int col = tid & 127;
    const int half = tid >> 7;
    const int row0 = blockIdx.x * 32;

    float acc[16];
#pragma unroll
    for (int i = 0; i < 16; ++i) acc[i] = 0.f;

    for (int k0 = 0; k0 < D; k0 += 16) {
        // stage weight chunks: 16x128 each
        for (int j = tid; j < 16 * D; j += 256) {
            int kk = j >> 7, c = j & 127;
            sW[0][kk][c] = Wl[(size_t)(k0 + kk) * D + c];
            sW[1][kk][c] = Wr[(size_t)(k0 + kk) * D + c];
        }
        // stage h/agg tiles: 32 rows x 16 k
        for (int j = tid; j < 32 * 16; j += 256) {
            int r = j >> 4, kk = j & 15;
            int row = row0 + r;
            if (row < N_) {
                sH[r][kk] = hin[(size_t)row * D + k0 + kk];
                sA[r][kk] = agg[(size_t)row * D + k0 + kk] * inv_deg[row];
            } else {
                sH[r][kk] = 0.f;
                sA[r][kk] = 0.f;
            }
        }
        __syncthreads();
#pragma unroll
        for (int kk = 0; kk < 16; ++kk) {
            float wl = sW[0][kk][col];
            float wr = sW[1][kk][col];
#pragma unroll
            for (int r = 0; r < 16; ++r) {
                int rg = half * 16 + r;
                acc[r] += sA[rg][kk] * wl + sH[rg][kk] * wr;
            }
        }
        __syncthreads();
    }

    float b = bias[col];
#pragma unroll
    for (int r = 0; r < 16; ++r) {
        int rg = half * 16 + r;
        int row = row0 + rg;
        if (row < N_) {
            float v = acc[r] + b;
            if (do_relu) v = fmaxf(v, 0.f);
            out[(size_t)row * D + col] = v;
        }
    }
}

extern "C" void kernel_launch(void* const* d_in, const int* in_sizes, int n_in,
                              void* d_out, int out_size, void* d_ws, size_t ws_size,
                              hipStream_t stream) {
    const float* x = (const float*)d_in[0];
    const int* edge = (const int*)d_in[1];
    const float* Wl[3] = {(const float*)d_in[2], (const float*)d_in[5], (const float*)d_in[8]};
    const float* Wr[3] = {(const float*)d_in[3], (const float*)d_in[6], (const float*)d_in[9]};
    const float* bs[3] = {(const float*)d_in[4], (const float*)d_in[7], (const float*)d_in[10]};

    const int N_ = in_sizes[0] / D;
    const int E_ = in_sizes[1] / 2;
    const int* src = edge;
    const int* dst = edge + E_;

    char* ws = (char*)d_ws;
    size_t fmat = (size_t)N_ * D * sizeof(float);
    float* agg = (float*)ws;                            // N*128 f32
    float* hA = (float*)(ws + fmat);                    // N*128 f32
    float* inv_deg = (float*)(ws + 2 * fmat);           // N f32
    int* deg_i = (int*)(ws + 2 * fmat + (size_t)N_ * 4);  // N i32
    float* outf = (float*)d_out;

    // degrees (dst-only): once, reused by all layers
    hipMemsetAsync(deg_i, 0, (size_t)N_ * sizeof(int), stream);
    deg_count_kernel<<<(E_ + 255) / 256, 256, 0, stream>>>(dst, deg_i, E_);
    inv_deg_kernel<<<(N_ + 255) / 256, 256, 0, stream>>>(deg_i, inv_deg, N_);

    const float* hin = x;
    float* houts[3] = {hA, outf, outf};
    for (int l = 0; l < 3; ++l) {
        hipMemsetAsync(agg, 0, fmat, stream);
        long long threads = (long long)E_ * 32;
        scatter_kernel<<<(int)((threads + 255) / 256), 256, 0, stream>>>(hin, src, dst, agg, E_);
        sage_layer_gemm<<<(N_ + 31) / 32, 256, 0, stream>>>(hin, agg, inv_deg, Wl[l], Wr[l],
                                                            bs[l], houts[l], N_, l < 2 ? 1 : 0);
        hin = houts[l];
    }
}

// Round 2
// 745.795 us; speedup vs baseline: 4.9557x; 4.9557x over previous
//
#include <hip/hip_runtime.h>
#include <hip/hip_bf16.h>

#define D 128

// ---------------- degree count (dst-only, once per call) ----------------
__global__ void deg_count_kernel(const int* __restrict__ dst, int* __restrict__ deg,
                                 int E_) {
    int e = blockIdx.x * blockDim.x + threadIdx.x;
    if (e < E_) atomicAdd(&deg[dst[e]], 1);
}

// ---------------- single-block exclusive scan over deg → row_start --------
__global__ __launch_bounds__(256) void scan_kernel(const int* __restrict__ deg,
                                                   int* __restrict__ row_start,
                                                   float* __restrict__ inv_deg, int N_) {
    const int T = 256;
    int tid = threadIdx.x;
    int chunk = (N_ + T - 1) / T;
    int beg = tid * chunk;
    int end = beg + chunk;
    if (end > N_) end = N_;
    if (beg > N_) beg = N_;

    int local = 0;
    for (int i = beg; i < end; ++i) local += deg[i];

    // inclusive shuffle-scan within wave
    int lane = tid & 63, wid = tid >> 6;
    int v = local;
#pragma unroll
    for (int off = 1; off < 64; off <<= 1) {
        int n = __shfl_up(v, off, 64);
        if (lane >= off) v += n;
    }
    __shared__ int wsum[4];
    if (lane == 63) wsum[wid] = v;
    __syncthreads();
    int wofs = 0;
    for (int w = 0; w < wid; ++w) wofs += wsum[w];
    int excl = wofs + v - local;  // exclusive prefix of this thread's chunk

    int run = excl;
    for (int i = beg; i < end; ++i) {
        row_start[i] = run;
        int d = deg[i];
        inv_deg[i] = 1.0f / (float)(d > 0 ? d : 1);
        run += d;
    }
    if (tid == T - 1) row_start[N_] = run;
}

// ---------------- CSR placement: csr_src grouped by dst -------------------
__global__ void place_kernel(const int* __restrict__ src, const int* __restrict__ dst,
                             const int* __restrict__ row_start, int* __restrict__ cursor,
                             int* __restrict__ csr_src, int E_) {
    int e = blockIdx.x * blockDim.x + threadIdx.x;
    if (e >= E_) return;
    int d = dst[e];
    int pos = row_start[d] + atomicAdd(&cursor[d], 1);
    csr_src[pos] = src[e];
}

// ---------------- gather-mean: agg[n] = mean over incoming x[src] ---------
// one wave per node; lane owns a float2 column pair (64*8B = 512B = one row)
__global__ __launch_bounds__(256) void gather_mean_kernel(
    const float* __restrict__ h, const int* __restrict__ row_start,
    const int* __restrict__ csr_src, const float* __restrict__ inv_deg,
    float* __restrict__ agg, int N_) {
    int node = blockIdx.x * 4 + (threadIdx.x >> 6);
    int lane = threadIdx.x & 63;
    if (node >= N_) return;
    int beg = row_start[node];
    int end = row_start[node + 1];

    float2 acc0 = {0.f, 0.f}, acc1 = {0.f, 0.f};
    int e = beg;
    for (; e + 1 < end; e += 2) {
        int s0 = csr_src[e];
        int s1 = csr_src[e + 1];
        float2 v0 = reinterpret_cast<const float2*>(h + (size_t)s0 * D)[lane];
        float2 v1 = reinterpret_cast<const float2*>(h + (size_t)s1 * D)[lane];
        acc0.x += v0.x; acc0.y += v0.y;
        acc1.x += v1.x; acc1.y += v1.y;
    }
    if (e < end) {
        int s0 = csr_src[e];
        float2 v0 = reinterpret_cast<const float2*>(h + (size_t)s0 * D)[lane];
        acc0.x += v0.x; acc0.y += v0.y;
    }
    float sc = inv_deg[node];
    float2 r;
    r.x = (acc0.x + acc1.x) * sc;
    r.y = (acc0.y + acc1.y) * sc;
    reinterpret_cast<float2*>(agg + (size_t)node * D)[lane] = r;
}

// ---------------- fused layer GEMM: out = agg@Wl + b + hin@Wr -------------
__global__ __launch_bounds__(256) void sage_layer_gemm(
    const float* __restrict__ hin, const float* __restrict__ agg,
    const float* __restrict__ Wl, const float* __restrict__ Wr,
    const float* __restrict__ bias, float* __restrict__ out, int N_, int do_relu) {
    __shared__ float sW[2][16][D];
    __shared__ float sH[32][17];
    __shared__ float sA[32][17];

    const int tid = threadIdx.x;
    const int col = tid & 127;
    const int half = tid >> 7;
    const int row0 = blockIdx.x * 32;

    float acc[16];
#pragma unroll
    for (int i = 0; i < 16; ++i) acc[i] = 0.f;

    for (int k0 = 0; k0 < D; k0 += 16) {
        for (int j = tid; j < 16 * D; j += 256) {
            int kk = j >> 7, c = j & 127;
            sW[0][kk][c] = Wl[(size_t)(k0 + kk) * D + c];
            sW[1][kk][c] = Wr[(size_t)(k0 + kk) * D + c];
        }
        for (int j = tid; j < 32 * 16; j += 256) {
            int r = j >> 4, kk = j & 15;
            int row = row0 + r;
            if (row < N_) {
                sH[r][kk] = hin[(size_t)row * D + k0 + kk];
                sA[r][kk] = agg[(size_t)row * D + k0 + kk];
            } else {
                sH[r][kk] = 0.f;
                sA[r][kk] = 0.f;
            }
        }
        __syncthreads();
#pragma unroll
        for (int kk = 0; kk < 16; ++kk) {
            float wl = sW[0][kk][col];
            float wr = sW[1][kk][col];
#pragma unroll
            for (int r = 0; r < 16; ++r) {
                int rg = half * 16 + r;
                acc[r] += sA[rg][kk] * wl + sH[rg][kk] * wr;
            }
        }
        __syncthreads();
    }

    float b = bias[col];
#pragma unroll
    for (int r = 0; r < 16; ++r) {
        int rg = half * 16 + r;
        int row = row0 + rg;
        if (row < N_) {
            float v = acc[r] + b;
            if (do_relu) v = fmaxf(v, 0.f);
            out[(size_t)row * D + col] = v;
        }
    }
}

extern "C" void kernel_launch(void* const* d_in, const int* in_sizes, int n_in,
                              void* d_out, int out_size, void* d_ws, size_t ws_size,
                              hipStream_t stream) {
    const float* x = (const float*)d_in[0];
    const int* edge = (const int*)d_in[1];
    const float* Wl[3] = {(const float*)d_in[2], (const float*)d_in[5], (const float*)d_in[8]};
    const float* Wr[3] = {(const float*)d_in[3], (const float*)d_in[6], (const float*)d_in[9]};
    const float* bs[3] = {(const float*)d_in[4], (const float*)d_in[7], (const float*)d_in[10]};

    const int N_ = in_sizes[0] / D;
    const int E_ = in_sizes[1] / 2;
    const int* src = edge;
    const int* dst = edge + E_;

    char* ws = (char*)d_ws;
    size_t fmat = (size_t)N_ * D * sizeof(float);
    float* agg = (float*)ws;                       // N*128 f32
    float* hA = (float*)(ws + fmat);               // N*128 f32
    char* p = ws + 2 * fmat;
    int* deg_i = (int*)p;            p += (size_t)N_ * 4;
    int* row_start = (int*)p;        p += (size_t)(N_ + 1) * 4;
    int* cursor = (int*)p;           p += (size_t)N_ * 4;
    float* inv_deg = (float*)p;      p += (size_t)N_ * 4;
    int* csr_src = (int*)p;          p += (size_t)E_ * 4;
    float* outf = (float*)d_out;

    // ---- CSR build (once; reused by all 3 layers) ----
    hipMemsetAsync(deg_i, 0, (size_t)N_ * sizeof(int), stream);
    hipMemsetAsync(cursor, 0, (size_t)N_ * sizeof(int), stream);
    deg_count_kernel<<<(E_ + 255) / 256, 256, 0, stream>>>(dst, deg_i, E_);
    scan_kernel<<<1, 256, 0, stream>>>(deg_i, row_start, inv_deg, N_);
    place_kernel<<<(E_ + 255) / 256, 256, 0, stream>>>(src, dst, row_start, cursor, csr_src, E_);

    const float* hin = x;
    float* houts[3] = {hA, outf, outf};
    for (int l = 0; l < 3; ++l) {
        gather_mean_kernel<<<(N_ + 3) / 4, 256, 0, stream>>>(hin, row_start, csr_src,
                                                             inv_deg, agg, N_);
        sage_layer_gemm<<<(N_ + 31) / 32, 256, 0, stream>>>(hin, agg, Wl[l], Wr[l],
                                                            bs[l], houts[l], N_, l < 2 ? 1 : 0);
        hin = houts[l];
    }
}

// Round 3
// 353.790 us; speedup vs baseline: 10.4467x; 2.1080x over previous
//
#include <hip/hip_runtime.h>
#include <hip/hip_bf16.h>

#define D 128

typedef __attribute__((ext_vector_type(4))) float f32x4;
typedef __attribute__((ext_vector_type(8))) short bf16x8;

static __device__ __forceinline__ unsigned short f2bf(float f) {
    union { float f; unsigned int u; } v; v.f = f;
    unsigned int r = v.u + 0x7fffu + ((v.u >> 16) & 1u);
    return (unsigned short)(r >> 16);
}
static __device__ __forceinline__ float bf2f_lo(unsigned int v) {
    union { unsigned int u; float f; } x; x.u = v << 16; return x.f;
}
static __device__ __forceinline__ float bf2f_hi(unsigned int v) {
    union { unsigned int u; float f; } x; x.u = v & 0xffff0000u; return x.f;
}

// ---------------- degree count (dst-only, once per call) ----------------
__global__ void deg_count_kernel(const int* __restrict__ dst, int* __restrict__ deg,
                                 int E_) {
    int e = blockIdx.x * blockDim.x + threadIdx.x;
    if (e < E_) atomicAdd(&deg[dst[e]], 1);
}

// ---------------- single-block exclusive scan over deg → row_start --------
__global__ __launch_bounds__(256) void scan_kernel(const int* __restrict__ deg,
                                                   int* __restrict__ row_start,
                                                   float* __restrict__ inv_deg, int N_) {
    const int T = 256;
    int tid = threadIdx.x;
    int chunk = (N_ + T - 1) / T;
    int beg = tid * chunk;
    int end = beg + chunk;
    if (end > N_) end = N_;
    if (beg > N_) beg = N_;

    int local = 0;
    for (int i = beg; i < end; ++i) local += deg[i];

    int lane = tid & 63, wid = tid >> 6;
    int v = local;
#pragma unroll
    for (int off = 1; off < 64; off <<= 1) {
        int n = __shfl_up(v, off, 64);
        if (lane >= off) v += n;
    }
    __shared__ int wsum[4];
    if (lane == 63) wsum[wid] = v;
    __syncthreads();
    int wofs = 0;
    for (int w = 0; w < wid; ++w) wofs += wsum[w];
    int excl = wofs + v - local;

    int run = excl;
    for (int i = beg; i < end; ++i) {
        row_start[i] = run;
        int d = deg[i];
        inv_deg[i] = 1.0f / (float)(d > 0 ? d : 1);
        run += d;
    }
    if (tid == T - 1) row_start[N_] = run;
}

// ---------------- CSR placement: csr_src grouped by dst -------------------
__global__ void place_kernel(const int* __restrict__ src, const int* __restrict__ dst,
                             const int* __restrict__ row_start, int* __restrict__ cursor,
                             int* __restrict__ csr_src, int E_) {
    int e = blockIdx.x * blockDim.x + threadIdx.x;
    if (e >= E_) return;
    int d = dst[e];
    int pos = row_start[d] + atomicAdd(&cursor[d], 1);
    csr_src[pos] = src[e];
}

// ---------------- x (f32) -> bf16 -----------------------------------------
__global__ __launch_bounds__(256) void cvt_bf16_kernel(const float* __restrict__ in,
                                                       unsigned short* __restrict__ out,
                                                       int n4) {
    int i = blockIdx.x * blockDim.x + threadIdx.x;
    if (i >= n4) return;
    float4 v = reinterpret_cast<const float4*>(in)[i];
    ushort4 o;
    o.x = f2bf(v.x); o.y = f2bf(v.y); o.z = f2bf(v.z); o.w = f2bf(v.w);
    reinterpret_cast<ushort4*>(out)[i] = o;
}

// ---------------- gather-mean (bf16 in, bf16 out) -------------------------
// one wave per node; lane owns one uint = 2 bf16 columns (64*4B = 256B row)
__global__ __launch_bounds__(256) void gather_mean_bf16(
    const unsigned short* __restrict__ hb, const int* __restrict__ row_start,
    const int* __restrict__ csr_src, const float* __restrict__ inv_deg,
    unsigned short* __restrict__ aggb, int N_) {
    int node = blockIdx.x * 4 + (threadIdx.x >> 6);
    int lane = threadIdx.x & 63;
    if (node >= N_) return;
    int beg = row_start[node];
    int end = row_start[node + 1];

    float ax = 0.f, ay = 0.f, bx = 0.f, by = 0.f;
    int e = beg;
    for (; e + 1 < end; e += 2) {
        int s0 = csr_src[e];
        int s1 = csr_src[e + 1];
        unsigned int v0 = reinterpret_cast<const unsigned int*>(hb + (size_t)s0 * D)[lane];
        unsigned int v1 = reinterpret_cast<const unsigned int*>(hb + (size_t)s1 * D)[lane];
        ax += bf2f_lo(v0); ay += bf2f_hi(v0);
        bx += bf2f_lo(v1); by += bf2f_hi(v1);
    }
    if (e < end) {
        unsigned int v0 = reinterpret_cast<const unsigned int*>(hb + (size_t)csr_src[e] * D)[lane];
        ax += bf2f_lo(v0); ay += bf2f_hi(v0);
    }
    float sc = inv_deg[node];
    unsigned int r = (unsigned int)f2bf((ax + bx) * sc) |
                     ((unsigned int)f2bf((ay + by) * sc) << 16);
    reinterpret_cast<unsigned int*>(aggb + (size_t)node * D)[lane] = r;
}

// ---------------- fused MFMA GEMM: out = [agg|h] @ [Wl;Wr] + b -------------
// 256 thr = 4 waves, BM=128 (32 rows/wave), N=128 cols, K=256.
// Wt staged in LDS as bf16 [col][k] with +8 pad. A-frags straight from global.
// MODE 0: bf16 out + relu; MODE 1: f32 out, no relu.
template <int MODE>
__global__ __launch_bounds__(256) void sage_gemm_mfma(
    const unsigned short* __restrict__ hinb, const unsigned short* __restrict__ aggb,
    const float* __restrict__ Wl, const float* __restrict__ Wr,
    const float* __restrict__ bias, void* __restrict__ out, int N_) {
    __shared__ unsigned short sWt[128][264];  // [col][k 0..255], +8 pad (16B)

    const int tid = threadIdx.x;
    // stage W^T (bf16): Wl -> k 0..127, Wr -> k 128..255
    for (int idx = tid; idx < 128 * 128; idx += 256) {
        int k = idx >> 7, c = idx & 127;
        sWt[c][k] = f2bf(Wl[idx]);
        sWt[c][128 + k] = f2bf(Wr[idx]);
    }
    __syncthreads();

    const int lane = tid & 63;
    const int w = tid >> 6;
    const int q = lane >> 4;      // 0..3
    const int c = lane & 15;      // 0..15
    const int R = blockIdx.x * 128 + w * 32;

    int r0 = R + c;       if (r0 > N_ - 1) r0 = N_ - 1;
    int r1 = R + 16 + c;  if (r1 > N_ - 1) r1 = N_ - 1;

    f32x4 acc[2][8];
#pragma unroll
    for (int m = 0; m < 2; ++m)
#pragma unroll
        for (int n = 0; n < 8; ++n) acc[m][n] = (f32x4){0.f, 0.f, 0.f, 0.f};

#pragma unroll
    for (int ks = 0; ks < 8; ++ks) {
        int kg = ks * 32 + q * 8;
        const unsigned short* base = (kg < 128) ? (aggb + kg) : (hinb + (kg - 128));
        bf16x8 a0 = *reinterpret_cast<const bf16x8*>(base + (size_t)r0 * D);
        bf16x8 a1 = *reinterpret_cast<const bf16x8*>(base + (size_t)r1 * D);
#pragma unroll
        for (int n = 0; n < 8; ++n) {
            bf16x8 b = *reinterpret_cast<const bf16x8*>(&sWt[n * 16 + c][ks * 32 + q * 8]);
            acc[0][n] = __builtin_amdgcn_mfma_f32_16x16x32_bf16(a0, b, acc[0][n], 0, 0, 0);
            acc[1][n] = __builtin_amdgcn_mfma_f32_16x16x32_bf16(a1, b, acc[1][n], 0, 0, 0);
        }
    }

    // epilogue: C row=(q*4+r), col=c within each 16x16 frag  [m89-verified]
    unsigned short* outb = (unsigned short*)out;
    float* outf = (float*)out;
#pragma unroll
    for (int n = 0; n < 8; ++n) {
        int col = n * 16 + c;
        float bv = bias[col];
#pragma unroll
        for (int m = 0; m < 2; ++m) {
#pragma unroll
            for (int r = 0; r < 4; ++r) {
                int row = R + m * 16 + q * 4 + r;
                if (row < N_) {
                    float v = acc[m][n][r] + bv;
                    if (MODE == 0) {
                        v = fmaxf(v, 0.f);
                        outb[(size_t)row * D + col] = f2bf(v);
                    } else {
                        outf[(size_t)row * D + col] = v;
                    }
                }
            }
        }
    }
}

extern "C" void kernel_launch(void* const* d_in, const int* in_sizes, int n_in,
                              void* d_out, int out_size, void* d_ws, size_t ws_size,
                              hipStream_t stream) {
    const float* x = (const float*)d_in[0];
    const int* edge = (const int*)d_in[1];
    const float* Wl[3] = {(const float*)d_in[2], (const float*)d_in[5], (const float*)d_in[8]};
    const float* Wr[3] = {(const float*)d_in[3], (const float*)d_in[6], (const float*)d_in[9]};
    const float* bs[3] = {(const float*)d_in[4], (const float*)d_in[7], (const float*)d_in[10]};

    const int N_ = in_sizes[0] / D;
    const int E_ = in_sizes[1] / 2;
    const int* src = edge;
    const int* dst = edge + E_;

    char* ws = (char*)d_ws;
    size_t bmat = (size_t)N_ * D * sizeof(unsigned short);  // 10.24 MB
    unsigned short* xb = (unsigned short*)ws;                // also reused as h2b
    unsigned short* h1b = (unsigned short*)(ws + bmat);
    unsigned short* aggb = (unsigned short*)(ws + 2 * bmat);
    char* p = ws + 3 * bmat;
    int* deg_i = (int*)p;       p += (size_t)N_ * 4;
    int* row_start = (int*)p;   p += (size_t)(N_ + 1) * 4;
    int* cursor = (int*)p;      p += (size_t)N_ * 4;
    float* inv_deg = (float*)p; p += (size_t)N_ * 4;
    int* csr_src = (int*)p;     p += (size_t)E_ * 4;

    // ---- CSR build (once; reused by all 3 layers) ----
    hipMemsetAsync(deg_i, 0, (size_t)N_ * sizeof(int), stream);
    hipMemsetAsync(cursor, 0, (size_t)N_ * sizeof(int), stream);
    deg_count_kernel<<<(E_ + 255) / 256, 256, 0, stream>>>(dst, deg_i, E_);
    scan_kernel<<<1, 256, 0, stream>>>(deg_i, row_start, inv_deg, N_);
    place_kernel<<<(E_ + 255) / 256, 256, 0, stream>>>(src, dst, row_start, cursor, csr_src, E_);

    // x -> bf16
    int n4 = N_ * D / 4;
    cvt_bf16_kernel<<<(n4 + 255) / 256, 256, 0, stream>>>(x, xb, n4);

    int gemm_blocks = (N_ + 127) / 128;
    unsigned short* h2b = xb;  // x dead after layer 0

    // layer 0
    gather_mean_bf16<<<(N_ + 3) / 4, 256, 0, stream>>>(xb, row_start, csr_src, inv_deg, aggb, N_);
    sage_gemm_mfma<0><<<gemm_blocks, 256, 0, stream>>>(xb, aggb, Wl[0], Wr[0], bs[0], h1b, N_);
    // layer 1
    gather_mean_bf16<<<(N_ + 3) / 4, 256, 0, stream>>>(h1b, row_start, csr_src, inv_deg, aggb, N_);
    sage_gemm_mfma<0><<<gemm_blocks, 256, 0, stream>>>(h1b, aggb, Wl[1], Wr[1], bs[1], h2b, N_);
    // layer 2
    gather_mean_bf16<<<(N_ + 3) / 4, 256, 0, stream>>>(h2b, row_start, csr_src, inv_deg, aggb, N_);
    sage_gemm_mfma<1><<<gemm_blocks, 256, 0, stream>>>(h2b, aggb, Wl[2], Wr[2], bs[2], d_out, N_);
}

// Round 4
// 270.773 us; speedup vs baseline: 13.6496x; 1.3066x over previous
//
#include <hip/hip_runtime.h>
#include <hip/hip_bf16.h>

#define D 128

typedef __attribute__((ext_vector_type(4))) float f32x4;
typedef __attribute__((ext_vector_type(8))) short bf16x8;

static __device__ __forceinline__ unsigned short f2bf(float f) {
    union { float f; unsigned int u; } v; v.f = f;
    unsigned int r = v.u + 0x7fffu + ((v.u >> 16) & 1u);
    return (unsigned short)(r >> 16);
}
static __device__ __forceinline__ float bf2f_lo(unsigned int v) {
    union { unsigned int u; float f; } x; x.u = v << 16; return x.f;
}
static __device__ __forceinline__ float bf2f_hi(unsigned int v) {
    union { unsigned int u; float f; } x; x.u = v & 0xffff0000u; return x.f;
}

// ---------------- degree count (dst-only, once per call) ----------------
__global__ void deg_count_kernel(const int* __restrict__ dst, int* __restrict__ deg,
                                 int E_) {
    int e = blockIdx.x * blockDim.x + threadIdx.x;
    if (e < E_) atomicAdd(&deg[dst[e]], 1);
}

// ---------------- parallel scan, pass A: per-block sums -------------------
__global__ __launch_bounds__(256) void block_sum_kernel(const int* __restrict__ deg,
                                                        int* __restrict__ blockSums,
                                                        int N_) {
    int tid = threadIdx.x;
    int i = blockIdx.x * 256 + tid;
    int v = (i < N_) ? deg[i] : 0;
    int lane = tid & 63, wid = tid >> 6;
#pragma unroll
    for (int off = 32; off > 0; off >>= 1) v += __shfl_down(v, off, 64);
    __shared__ int ws[4];
    if (lane == 0) ws[wid] = v;
    __syncthreads();
    if (tid == 0) blockSums[blockIdx.x] = ws[0] + ws[1] + ws[2] + ws[3];
}

// ---------------- pass B: exclusive scan of block sums (nb <= 256) --------
__global__ __launch_bounds__(256) void scan_sums_kernel(const int* __restrict__ blockSums,
                                                        int* __restrict__ blockOffs,
                                                        int nb, int* __restrict__ row_start,
                                                        int N_, int E_) {
    int tid = threadIdx.x;
    int v = (tid < nb) ? blockSums[tid] : 0;
    int lane = tid & 63, wid = tid >> 6;
    int inc = v;
#pragma unroll
    for (int off = 1; off < 64; off <<= 1) {
        int n = __shfl_up(inc, off, 64);
        if (lane >= off) inc += n;
    }
    __shared__ int ws[4];
    if (lane == 63) ws[wid] = inc;
    __syncthreads();
    int wofs = 0;
    for (int w = 0; w < wid; ++w) wofs += ws[w];
    if (tid < nb) blockOffs[tid] = wofs + inc - v;
    if (tid == 0) row_start[N_] = E_;
}

// ---------------- pass C: intra-block scan + write row_start/inv_deg ------
__global__ __launch_bounds__(256) void scan_write_kernel(const int* __restrict__ deg,
                                                         const int* __restrict__ blockOffs,
                                                         int* __restrict__ row_start,
                                                         float* __restrict__ inv_deg,
                                                         int N_) {
    int tid = threadIdx.x;
    int i = blockIdx.x * 256 + tid;
    int v = (i < N_) ? deg[i] : 0;
    int lane = tid & 63, wid = tid >> 6;
    int inc = v;
#pragma unroll
    for (int off = 1; off < 64; off <<= 1) {
        int n = __shfl_up(inc, off, 64);
        if (lane >= off) inc += n;
    }
    __shared__ int ws[4];
    if (lane == 63) ws[wid] = inc;
    __syncthreads();
    int wofs = 0;
    for (int w = 0; w < wid; ++w) wofs += ws[w];
    if (i < N_) {
        row_start[i] = blockOffs[blockIdx.x] + wofs + inc - v;
        inv_deg[i] = 1.0f / (float)(v > 0 ? v : 1);
    }
}

// ---------------- CSR placement: csr_src grouped by dst -------------------
__global__ void place_kernel(const int* __restrict__ src, const int* __restrict__ dst,
                             const int* __restrict__ row_start, int* __restrict__ cursor,
                             int* __restrict__ csr_src, int E_) {
    int e = blockIdx.x * blockDim.x + threadIdx.x;
    if (e >= E_) return;
    int d = dst[e];
    int pos = row_start[d] + atomicAdd(&cursor[d], 1);
    csr_src[pos] = src[e];
}

// ---------------- x (f32) -> bf16 -----------------------------------------
__global__ __launch_bounds__(256) void cvt_bf16_kernel(const float* __restrict__ in,
                                                       unsigned short* __restrict__ out,
                                                       int n4) {
    int i = blockIdx.x * blockDim.x + threadIdx.x;
    if (i >= n4) return;
    float4 v = reinterpret_cast<const float4*>(in)[i];
    ushort4 o;
    o.x = f2bf(v.x); o.y = f2bf(v.y); o.z = f2bf(v.z); o.w = f2bf(v.w);
    reinterpret_cast<ushort4*>(out)[i] = o;
}

// ---------------- gather-mean (bf16 in, bf16 out) -------------------------
// one wave per node; lane owns one uint = 2 bf16 columns (64*4B = 256B row)
__global__ __launch_bounds__(256) void gather_mean_bf16(
    const unsigned short* __restrict__ hb, const int* __restrict__ row_start,
    const int* __restrict__ csr_src, const float* __restrict__ inv_deg,
    unsigned short* __restrict__ aggb, int N_) {
    int node = blockIdx.x * 4 + (threadIdx.x >> 6);
    int lane = threadIdx.x & 63;
    if (node >= N_) return;
    int beg = row_start[node];
    int end = row_start[node + 1];

    float ax = 0.f, ay = 0.f, bx = 0.f, by = 0.f;
    int e = beg;
    for (; e + 1 < end; e += 2) {
        int s0 = csr_src[e];
        int s1 = csr_src[e + 1];
        unsigned int v0 = reinterpret_cast<const unsigned int*>(hb + (size_t)s0 * D)[lane];
        unsigned int v1 = reinterpret_cast<const unsigned int*>(hb + (size_t)s1 * D)[lane];
        ax += bf2f_lo(v0); ay += bf2f_hi(v0);
        bx += bf2f_lo(v1); by += bf2f_hi(v1);
    }
    if (e < end) {
        unsigned int v0 = reinterpret_cast<const unsigned int*>(hb + (size_t)csr_src[e] * D)[lane];
        ax += bf2f_lo(v0); ay += bf2f_hi(v0);
    }
    float sc = inv_deg[node];
    unsigned int r = (unsigned int)f2bf((ax + bx) * sc) |
                     ((unsigned int)f2bf((ay + by) * sc) << 16);
    reinterpret_cast<unsigned int*>(aggb + (size_t)node * D)[lane] = r;
}

// ---------------- fused MFMA GEMM: out = [agg|h] @ [Wl;Wr] + b -------------
// 256 thr = 4 waves, BM=128 (32 rows/wave), N=128 cols, K=256.
// Wt staged in LDS as bf16 [col][k] with +8 pad. A-frags straight from global.
// MODE 0: bf16 out + relu; MODE 1: f32 out, no relu.
template <int MODE>
__global__ __launch_bounds__(256) void sage_gemm_mfma(
    const unsigned short* __restrict__ hinb, const unsigned short* __restrict__ aggb,
    const float* __restrict__ Wl, const float* __restrict__ Wr,
    const float* __restrict__ bias, void* __restrict__ out, int N_) {
    __shared__ unsigned short sWt[128][264];  // [col][k 0..255], +8 pad (16B)

    const int tid = threadIdx.x;
    // stage W^T (bf16): Wl -> k 0..127, Wr -> k 128..255
    for (int idx = tid; idx < 128 * 128; idx += 256) {
        int k = idx >> 7, c = idx & 127;
        sWt[c][k] = f2bf(Wl[idx]);
        sWt[c][128 + k] = f2bf(Wr[idx]);
    }
    __syncthreads();

    const int lane = tid & 63;
    const int w = tid >> 6;
    const int q = lane >> 4;      // 0..3
    const int c = lane & 15;      // 0..15
    const int R = blockIdx.x * 128 + w * 32;

    int r0 = R + c;       if (r0 > N_ - 1) r0 = N_ - 1;
    int r1 = R + 16 + c;  if (r1 > N_ - 1) r1 = N_ - 1;

    f32x4 acc[2][8];
#pragma unroll
    for (int m = 0; m < 2; ++m)
#pragma unroll
        for (int n = 0; n < 8; ++n) acc[m][n] = (f32x4){0.f, 0.f, 0.f, 0.f};

#pragma unroll
    for (int ks = 0; ks < 8; ++ks) {
        int kg = ks * 32 + q * 8;
        const unsigned short* base = (kg < 128) ? (aggb + kg) : (hinb + (kg - 128));
        bf16x8 a0 = *reinterpret_cast<const bf16x8*>(base + (size_t)r0 * D);
        bf16x8 a1 = *reinterpret_cast<const bf16x8*>(base + (size_t)r1 * D);
#pragma unroll
        for (int n = 0; n < 8; ++n) {
            bf16x8 b = *reinterpret_cast<const bf16x8*>(&sWt[n * 16 + c][ks * 32 + q * 8]);
            acc[0][n] = __builtin_amdgcn_mfma_f32_16x16x32_bf16(a0, b, acc[0][n], 0, 0, 0);
            acc[1][n] = __builtin_amdgcn_mfma_f32_16x16x32_bf16(a1, b, acc[1][n], 0, 0, 0);
        }
    }

    // epilogue: C row=(q*4+r), col=c within each 16x16 frag  [m89-verified]
    unsigned short* outb = (unsigned short*)out;
    float* outf = (float*)out;
#pragma unroll
    for (int n = 0; n < 8; ++n) {
        int col = n * 16 + c;
        float bv = bias[col];
#pragma unroll
        for (int m = 0; m < 2; ++m) {
#pragma unroll
            for (int r = 0; r < 4; ++r) {
                int row = R + m * 16 + q * 4 + r;
                if (row < N_) {
                    float v = acc[m][n][r] + bv;
                    if (MODE == 0) {
                        v = fmaxf(v, 0.f);
                        outb[(size_t)row * D + col] = f2bf(v);
                    } else {
                        outf[(size_t)row * D + col] = v;
                    }
                }
            }
        }
    }
}

extern "C" void kernel_launch(void* const* d_in, const int* in_sizes, int n_in,
                              void* d_out, int out_size, void* d_ws, size_t ws_size,
                              hipStream_t stream) {
    const float* x = (const float*)d_in[0];
    const int* edge = (const int*)d_in[1];
    const float* Wl[3] = {(const float*)d_in[2], (const float*)d_in[5], (const float*)d_in[8]};
    const float* Wr[3] = {(const float*)d_in[3], (const float*)d_in[6], (const float*)d_in[9]};
    const float* bs[3] = {(const float*)d_in[4], (const float*)d_in[7], (const float*)d_in[10]};

    const int N_ = in_sizes[0] / D;
    const int E_ = in_sizes[1] / 2;
    const int* src = edge;
    const int* dst = edge + E_;

    char* ws = (char*)d_ws;
    size_t bmat = (size_t)N_ * D * sizeof(unsigned short);  // 10.24 MB
    unsigned short* xb = (unsigned short*)ws;                // also reused as h2b
    unsigned short* h1b = (unsigned short*)(ws + bmat);
    unsigned short* aggb = (unsigned short*)(ws + 2 * bmat);
    char* p = ws + 3 * bmat;
    int* deg_i = (int*)p;       p += (size_t)N_ * 4;
    int* row_start = (int*)p;   p += (size_t)(N_ + 1) * 4;
    int* cursor = (int*)p;      p += (size_t)N_ * 4;
    float* inv_deg = (float*)p; p += (size_t)N_ * 4;
    int* blockSums = (int*)p;   p += 1024;
    int* blockOffs = (int*)p;   p += 1024;
    int* csr_src = (int*)p;     p += (size_t)E_ * 4;

    const int nb = (N_ + 255) / 256;  // 157 <= 256

    // ---- CSR build (once; reused by all 3 layers) ----
    hipMemsetAsync(deg_i, 0, (size_t)N_ * sizeof(int), stream);
    hipMemsetAsync(cursor, 0, (size_t)N_ * sizeof(int), stream);
    deg_count_kernel<<<(E_ + 255) / 256, 256, 0, stream>>>(dst, deg_i, E_);
    block_sum_kernel<<<nb, 256, 0, stream>>>(deg_i, blockSums, N_);
    scan_sums_kernel<<<1, 256, 0, stream>>>(blockSums, blockOffs, nb, row_start, N_, E_);
    scan_write_kernel<<<nb, 256, 0, stream>>>(deg_i, blockOffs, row_start, inv_deg, N_);
    place_kernel<<<(E_ + 255) / 256, 256, 0, stream>>>(src, dst, row_start, cursor, csr_src, E_);

    // x -> bf16
    int n4 = N_ * D / 4;
    cvt_bf16_kernel<<<(n4 + 255) / 256, 256, 0, stream>>>(x, xb, n4);

    int gemm_blocks = (N_ + 127) / 128;
    unsigned short* h2b = xb;  // x dead after layer 0

    // layer 0
    gather_mean_bf16<<<(N_ + 3) / 4, 256, 0, stream>>>(xb, row_start, csr_src, inv_deg, aggb, N_);
    sage_gemm_mfma<0><<<gemm_blocks, 256, 0, stream>>>(xb, aggb, Wl[0], Wr[0], bs[0], h1b, N_);
    // layer 1
    gather_mean_bf16<<<(N_ + 3) / 4, 256, 0, stream>>>(h1b, row_start, csr_src, inv_deg, aggb, N_);
    sage_gemm_mfma<0><<<gemm_blocks, 256, 0, stream>>>(h1b, aggb, Wl[1], Wr[1], bs[1], h2b, N_);
    // layer 2
    gather_mean_bf16<<<(N_ + 3) / 4, 256, 0, stream>>>(h2b, row_start, csr_src, inv_deg, aggb, N_);
    sage_gemm_mfma<1><<<gemm_blocks, 256, 0, stream>>>(h2b, aggb, Wl[2], Wr[2], bs[2], d_out, N_);
}

// Round 5
// 219.451 us; speedup vs baseline: 16.8417x; 1.2339x over previous
//
#include <hip/hip_runtime.h>
#include <hip/hip_bf16.h>

#define D 128

typedef __attribute__((ext_vector_type(4))) float f32x4;
typedef __attribute__((ext_vector_type(8))) short bf16x8;

static __device__ __forceinline__ unsigned short f2bf(float f) {
    union { float f; unsigned int u; } v; v.f = f;
    unsigned int r = v.u + 0x7fffu + ((v.u >> 16) & 1u);
    return (unsigned short)(r >> 16);
}
static __device__ __forceinline__ float bf2f_lo(unsigned int v) {
    union { unsigned int u; float f; } x; x.u = v << 16; return x.f;
}
static __device__ __forceinline__ float bf2f_hi(unsigned int v) {
    union { unsigned int u; float f; } x; x.u = v & 0xffff0000u; return x.f;
}

// ---------------- degree count (dst-only, once per call) ----------------
__global__ void deg_count_kernel(const int* __restrict__ dst, int* __restrict__ deg,
                                 int E_) {
    int e = blockIdx.x * blockDim.x + threadIdx.x;
    if (e < E_) atomicAdd(&deg[dst[e]], 1);
}

// ---------------- parallel scan, pass A: per-block sums -------------------
__global__ __launch_bounds__(256) void block_sum_kernel(const int* __restrict__ deg,
                                                        int* __restrict__ blockSums,
                                                        int N_) {
    int tid = threadIdx.x;
    int i = blockIdx.x * 256 + tid;
    int v = (i < N_) ? deg[i] : 0;
    int lane = tid & 63, wid = tid >> 6;
#pragma unroll
    for (int off = 32; off > 0; off >>= 1) v += __shfl_down(v, off, 64);
    __shared__ int ws[4];
    if (lane == 0) ws[wid] = v;
    __syncthreads();
    if (tid == 0) blockSums[blockIdx.x] = ws[0] + ws[1] + ws[2] + ws[3];
}

// ---------------- pass B: exclusive scan of block sums (nb <= 256) --------
__global__ __launch_bounds__(256) void scan_sums_kernel(const int* __restrict__ blockSums,
                                                        int* __restrict__ blockOffs,
                                                        int nb, int* __restrict__ row_start,
                                                        int N_, int E_) {
    int tid = threadIdx.x;
    int v = (tid < nb) ? blockSums[tid] : 0;
    int lane = tid & 63, wid = tid >> 6;
    int inc = v;
#pragma unroll
    for (int off = 1; off < 64; off <<= 1) {
        int n = __shfl_up(inc, off, 64);
        if (lane >= off) inc += n;
    }
    __shared__ int ws[4];
    if (lane == 63) ws[wid] = inc;
    __syncthreads();
    int wofs = 0;
    for (int w = 0; w < wid; ++w) wofs += ws[w];
    if (tid < nb) blockOffs[tid] = wofs + inc - v;
    if (tid == 0) row_start[N_] = E_;
}

// ---------------- pass C: intra-block scan; also cursor = row_start -------
__global__ __launch_bounds__(256) void scan_write_kernel(const int* __restrict__ deg,
                                                         const int* __restrict__ blockOffs,
                                                         int* __restrict__ row_start,
                                                         int* __restrict__ cursor,
                                                         float* __restrict__ inv_deg,
                                                         int N_) {
    int tid = threadIdx.x;
    int i = blockIdx.x * 256 + tid;
    int v = (i < N_) ? deg[i] : 0;
    int lane = tid & 63, wid = tid >> 6;
    int inc = v;
#pragma unroll
    for (int off = 1; off < 64; off <<= 1) {
        int n = __shfl_up(inc, off, 64);
        if (lane >= off) inc += n;
    }
    __shared__ int ws[4];
    if (lane == 63) ws[wid] = inc;
    __syncthreads();
    int wofs = 0;
    for (int w = 0; w < wid; ++w) wofs += ws[w];
    if (i < N_) {
        int rs = blockOffs[blockIdx.x] + wofs + inc - v;
        row_start[i] = rs;
        cursor[i] = rs;
        inv_deg[i] = 1.0f / (float)(v > 0 ? v : 1);
    }
}

// ---------------- CSR placement: cursor pre-seeded with row_start ---------
__global__ void place_kernel(const int* __restrict__ src, const int* __restrict__ dst,
                             int* __restrict__ cursor, int* __restrict__ csr_src, int E_) {
    int e = blockIdx.x * blockDim.x + threadIdx.x;
    if (e >= E_) return;
    int pos = atomicAdd(&cursor[dst[e]], 1);
    csr_src[pos] = src[e];
}

// ---------------- x (f32) -> bf16 -----------------------------------------
__global__ __launch_bounds__(256) void cvt_bf16_kernel(const float* __restrict__ in,
                                                       unsigned short* __restrict__ out,
                                                       int n4) {
    int i = blockIdx.x * blockDim.x + threadIdx.x;
    if (i >= n4) return;
    float4 v = reinterpret_cast<const float4*>(in)[i];
    ushort4 o;
    o.x = f2bf(v.x); o.y = f2bf(v.y); o.z = f2bf(v.z); o.w = f2bf(v.w);
    reinterpret_cast<ushort4*>(out)[i] = o;
}

// ---------------- W^T prep: WtB[col][k] bf16, k<128 Wl, k>=128 Wr ---------
__global__ __launch_bounds__(256) void wt_prep(const float* __restrict__ Wl,
                                               const float* __restrict__ Wr,
                                               unsigned short* __restrict__ WtB) {
    int idx = blockIdx.x * 256 + threadIdx.x;  // 0..4095
    int c = idx >> 5;
    int g = idx & 31;
    int k0 = g * 8;
    const float* Wsrc = (k0 < 128) ? (Wl + (size_t)k0 * D + c)
                                   : (Wr + (size_t)(k0 - 128) * D + c);
    float v[8];
#pragma unroll
    for (int i = 0; i < 8; ++i) v[i] = Wsrc[(size_t)i * D];
    uint4 o;
    o.x = (unsigned int)f2bf(v[0]) | ((unsigned int)f2bf(v[1]) << 16);
    o.y = (unsigned int)f2bf(v[2]) | ((unsigned int)f2bf(v[3]) << 16);
    o.z = (unsigned int)f2bf(v[4]) | ((unsigned int)f2bf(v[5]) << 16);
    o.w = (unsigned int)f2bf(v[6]) | ((unsigned int)f2bf(v[7]) << 16);
    *reinterpret_cast<uint4*>(WtB + (size_t)c * 256 + k0) = o;
}

// ---------------- gather-mean: quarter-wave per edge, 8 rows in flight ----
// 16 lanes x 16B (uint4 = 8 bf16) cover one 256B row; 4 edges/wave/instr.
__global__ __launch_bounds__(256) void gather_mean_bf16(
    const unsigned short* __restrict__ hb, const int* __restrict__ row_start,
    const int* __restrict__ csr_src, const float* __restrict__ inv_deg,
    unsigned short* __restrict__ aggb, int N_) {
    int node = blockIdx.x * 4 + (threadIdx.x >> 6);
    int lane = threadIdx.x & 63;
    if (node >= N_) return;
    int beg = row_start[node];
    int end = row_start[node + 1];
    int q = lane >> 4;   // quarter 0..3: handles edges beg+q, beg+q+4, ...
    int t = lane & 15;   // covers cols 8t..8t+7

    float acc[8];
#pragma unroll
    for (int i = 0; i < 8; ++i) acc[i] = 0.f;

    int e = beg + q;
    for (; e + 4 < end; e += 8) {
        int s0 = csr_src[e];
        int s1 = csr_src[e + 4];
        uint4 v0 = reinterpret_cast<const uint4*>(hb + (size_t)s0 * D)[t];
        uint4 v1 = reinterpret_cast<const uint4*>(hb + (size_t)s1 * D)[t];
        acc[0] += bf2f_lo(v0.x); acc[1] += bf2f_hi(v0.x);
        acc[2] += bf2f_lo(v0.y); acc[3] += bf2f_hi(v0.y);
        acc[4] += bf2f_lo(v0.z); acc[5] += bf2f_hi(v0.z);
        acc[6] += bf2f_lo(v0.w); acc[7] += bf2f_hi(v0.w);
        acc[0] += bf2f_lo(v1.x); acc[1] += bf2f_hi(v1.x);
        acc[2] += bf2f_lo(v1.y); acc[3] += bf2f_hi(v1.y);
        acc[4] += bf2f_lo(v1.z); acc[5] += bf2f_hi(v1.z);
        acc[6] += bf2f_lo(v1.w); acc[7] += bf2f_hi(v1.w);
    }
    if (e < end) {
        uint4 v0 = reinterpret_cast<const uint4*>(hb + (size_t)csr_src[e] * D)[t];
        acc[0] += bf2f_lo(v0.x); acc[1] += bf2f_hi(v0.x);
        acc[2] += bf2f_lo(v0.y); acc[3] += bf2f_hi(v0.y);
        acc[4] += bf2f_lo(v0.z); acc[5] += bf2f_hi(v0.z);
        acc[6] += bf2f_lo(v0.w); acc[7] += bf2f_hi(v0.w);
    }
    // cross-quarter reduce: lanes {t, t+16, t+32, t+48} hold partial sums
#pragma unroll
    for (int i = 0; i < 8; ++i) {
        acc[i] += __shfl_xor(acc[i], 16, 64);
        acc[i] += __shfl_xor(acc[i], 32, 64);
    }
    if (q == 0) {
        float sc = inv_deg[node];
        uint4 o;
        o.x = (unsigned int)f2bf(acc[0] * sc) | ((unsigned int)f2bf(acc[1] * sc) << 16);
        o.y = (unsigned int)f2bf(acc[2] * sc) | ((unsigned int)f2bf(acc[3] * sc) << 16);
        o.z = (unsigned int)f2bf(acc[4] * sc) | ((unsigned int)f2bf(acc[5] * sc) << 16);
        o.w = (unsigned int)f2bf(acc[6] * sc) | ((unsigned int)f2bf(acc[7] * sc) << 16);
        reinterpret_cast<uint4*>(aggb + (size_t)node * D)[t] = o;
    }
}

// ---------------- fused MFMA GEMM: out = [agg|h] @ WtB^T + b --------------
// 256 thr = 4 waves, BM=128 (32 rows/wave), N=128 cols, K=256.
// WtB pre-converted bf16 [col][k]; staged to LDS via pure 16B copies.
// MODE 0: bf16 out + relu; MODE 1: f32 out, no relu.
template <int MODE>
__global__ __launch_bounds__(256) void sage_gemm_mfma(
    const unsigned short* __restrict__ hinb, const unsigned short* __restrict__ aggb,
    const unsigned short* __restrict__ WtB, const float* __restrict__ bias,
    void* __restrict__ out, int N_) {
    __shared__ unsigned short sWt[128][264];  // [col][k 0..255], +8 pad

    const int tid = threadIdx.x;
    for (int idx = tid; idx < 128 * 32; idx += 256) {
        int c = idx >> 5, g = idx & 31;
        *reinterpret_cast<uint4*>(&sWt[c][g * 8]) =
            reinterpret_cast<const uint4*>(WtB + (size_t)c * 256)[g];
    }
    __syncthreads();

    const int lane = tid & 63;
    const int w = tid >> 6;
    const int q = lane >> 4;      // 0..3
    const int c = lane & 15;      // 0..15
    const int R = blockIdx.x * 128 + w * 32;

    int r0 = R + c;       if (r0 > N_ - 1) r0 = N_ - 1;
    int r1 = R + 16 + c;  if (r1 > N_ - 1) r1 = N_ - 1;

    f32x4 acc[2][8];
#pragma unroll
    for (int m = 0; m < 2; ++m)
#pragma unroll
        for (int n = 0; n < 8; ++n) acc[m][n] = (f32x4){0.f, 0.f, 0.f, 0.f};

#pragma unroll
    for (int ks = 0; ks < 8; ++ks) {
        int kg = ks * 32 + q * 8;
        const unsigned short* base = (kg < 128) ? (aggb + kg) : (hinb + (kg - 128));
        bf16x8 a0 = *reinterpret_cast<const bf16x8*>(base + (size_t)r0 * D);
        bf16x8 a1 = *reinterpret_cast<const bf16x8*>(base + (size_t)r1 * D);
#pragma unroll
        for (int n = 0; n < 8; ++n) {
            bf16x8 b = *reinterpret_cast<const bf16x8*>(&sWt[n * 16 + c][ks * 32 + q * 8]);
            acc[0][n] = __builtin_amdgcn_mfma_f32_16x16x32_bf16(a0, b, acc[0][n], 0, 0, 0);
            acc[1][n] = __builtin_amdgcn_mfma_f32_16x16x32_bf16(a1, b, acc[1][n], 0, 0, 0);
        }
    }

    // epilogue: C row=(q*4+r), col=c within each 16x16 frag  [m89-verified]
    unsigned short* outb = (unsigned short*)out;
    float* outf = (float*)out;
#pragma unroll
    for (int n = 0; n < 8; ++n) {
        int col = n * 16 + c;
        float bv = bias[col];
#pragma unroll
        for (int m = 0; m < 2; ++m) {
#pragma unroll
            for (int r = 0; r < 4; ++r) {
                int row = R + m * 16 + q * 4 + r;
                if (row < N_) {
                    float v = acc[m][n][r] + bv;
                    if (MODE == 0) {
                        v = fmaxf(v, 0.f);
                        outb[(size_t)row * D + col] = f2bf(v);
                    } else {
                        outf[(size_t)row * D + col] = v;
                    }
                }
            }
        }
    }
}

extern "C" void kernel_launch(void* const* d_in, const int* in_sizes, int n_in,
                              void* d_out, int out_size, void* d_ws, size_t ws_size,
                              hipStream_t stream) {
    const float* x = (const float*)d_in[0];
    const int* edge = (const int*)d_in[1];
    const float* Wl[3] = {(const float*)d_in[2], (const float*)d_in[5], (const float*)d_in[8]};
    const float* Wr[3] = {(const float*)d_in[3], (const float*)d_in[6], (const float*)d_in[9]};
    const float* bs[3] = {(const float*)d_in[4], (const float*)d_in[7], (const float*)d_in[10]};

    const int N_ = in_sizes[0] / D;
    const int E_ = in_sizes[1] / 2;
    const int* src = edge;
    const int* dst = edge + E_;

    char* ws = (char*)d_ws;
    size_t bmat = (size_t)N_ * D * sizeof(unsigned short);  // 10.24 MB
    unsigned short* xb = (unsigned short*)ws;                // also reused as h2b
    unsigned short* h1b = (unsigned short*)(ws + bmat);
    unsigned short* aggb = (unsigned short*)(ws + 2 * bmat);
    char* p = ws + 3 * bmat;
    int* deg_i = (int*)p;       p += (size_t)N_ * 4;
    int* row_start = (int*)p;   p += (size_t)(N_ + 1) * 4;
    int* cursor = (int*)p;      p += (size_t)N_ * 4;
    float* inv_deg = (float*)p; p += (size_t)N_ * 4;
    int* blockSums = (int*)p;   p += 1024;
    int* blockOffs = (int*)p;   p += 1024;
    unsigned short* WtB = (unsigned short*)p; p += 3 * 128 * 256 * sizeof(unsigned short);
    int* csr_src = (int*)p;     p += (size_t)E_ * 4;

    const int nb = (N_ + 255) / 256;  // 157 <= 256

    // ---- CSR build (once; reused by all 3 layers) ----
    hipMemsetAsync(deg_i, 0, (size_t)N_ * sizeof(int), stream);
    deg_count_kernel<<<(E_ + 255) / 256, 256, 0, stream>>>(dst, deg_i, E_);
    block_sum_kernel<<<nb, 256, 0, stream>>>(deg_i, blockSums, N_);
    scan_sums_kernel<<<1, 256, 0, stream>>>(blockSums, blockOffs, nb, row_start, N_, E_);
    scan_write_kernel<<<nb, 256, 0, stream>>>(deg_i, blockOffs, row_start, cursor, inv_deg, N_);
    place_kernel<<<(E_ + 255) / 256, 256, 0, stream>>>(src, dst, cursor, csr_src, E_);

    // weight prep (all 3 layers) + x -> bf16
    for (int l = 0; l < 3; ++l)
        wt_prep<<<16, 256, 0, stream>>>(Wl[l], Wr[l], WtB + (size_t)l * 128 * 256);
    int n4 = N_ * D / 4;
    cvt_bf16_kernel<<<(n4 + 255) / 256, 256, 0, stream>>>(x, xb, n4);

    int gemm_blocks = (N_ + 127) / 128;
    unsigned short* h2b = xb;  // x dead after layer 0

    // layer 0
    gather_mean_bf16<<<(N_ + 3) / 4, 256, 0, stream>>>(xb, row_start, csr_src, inv_deg, aggb, N_);
    sage_gemm_mfma<0><<<gemm_blocks, 256, 0, stream>>>(xb, aggb, WtB, bs[0], h1b, N_);
    // layer 1
    gather_mean_bf16<<<(N_ + 3) / 4, 256, 0, stream>>>(h1b, row_start, csr_src, inv_deg, aggb, N_);
    sage_gemm_mfma<0><<<gemm_blocks, 256, 0, stream>>>(h1b, aggb, WtB + 128 * 256, bs[1], h2b, N_);
    // layer 2
    gather_mean_bf16<<<(N_ + 3) / 4, 256, 0, stream>>>(h2b, row_start, csr_src, inv_deg, aggb, N_);
    sage_gemm_mfma<1><<<gemm_blocks, 256, 0, stream>>>(h2b, aggb, WtB + 2 * 128 * 256, bs[2], d_out, N_);
}

// Round 6
// 201.886 us; speedup vs baseline: 18.3070x; 1.0870x over previous
//
#include <hip/hip_runtime.h>
#include <hip/hip_bf16.h>

#define D 128

typedef __attribute__((ext_vector_type(4))) float f32x4;
typedef __attribute__((ext_vector_type(8))) short bf16x8;

static __device__ __forceinline__ unsigned short f2bf(float f) {
    union { float f; unsigned int u; } v; v.f = f;
    unsigned int r = v.u + 0x7fffu + ((v.u >> 16) & 1u);
    return (unsigned short)(r >> 16);
}
static __device__ __forceinline__ float bf2f_lo(unsigned int v) {
    union { unsigned int u; float f; } x; x.u = v << 16; return x.f;
}
static __device__ __forceinline__ float bf2f_hi(unsigned int v) {
    union { unsigned int u; float f; } x; x.u = v & 0xffff0000u; return x.f;
}

// ---------------- degree count (dst-only, once per call) ----------------
__global__ void deg_count_kernel(const int* __restrict__ dst, int* __restrict__ deg,
                                 int E_) {
    int e = blockIdx.x * blockDim.x + threadIdx.x;
    if (e < E_) atomicAdd(&deg[dst[e]], 1);
}

// ---------------- parallel scan, pass A: per-block sums -------------------
__global__ __launch_bounds__(256) void block_sum_kernel(const int* __restrict__ deg,
                                                        int* __restrict__ blockSums,
                                                        int N_) {
    int tid = threadIdx.x;
    int i = blockIdx.x * 256 + tid;
    int v = (i < N_) ? deg[i] : 0;
    int lane = tid & 63, wid = tid >> 6;
#pragma unroll
    for (int off = 32; off > 0; off >>= 1) v += __shfl_down(v, off, 64);
    __shared__ int ws[4];
    if (lane == 0) ws[wid] = v;
    __syncthreads();
    if (tid == 0) blockSums[blockIdx.x] = ws[0] + ws[1] + ws[2] + ws[3];
}

// ---------------- pass B: exclusive scan of block sums (nb <= 256) --------
__global__ __launch_bounds__(256) void scan_sums_kernel(const int* __restrict__ blockSums,
                                                        int* __restrict__ blockOffs,
                                                        int nb, int* __restrict__ row_start,
                                                        int N_, int E_) {
    int tid = threadIdx.x;
    int v = (tid < nb) ? blockSums[tid] : 0;
    int lane = tid & 63, wid = tid >> 6;
    int inc = v;
#pragma unroll
    for (int off = 1; off < 64; off <<= 1) {
        int n = __shfl_up(inc, off, 64);
        if (lane >= off) inc += n;
    }
    __shared__ int ws[4];
    if (lane == 63) ws[wid] = inc;
    __syncthreads();
    int wofs = 0;
    for (int w = 0; w < wid; ++w) wofs += ws[w];
    if (tid < nb) blockOffs[tid] = wofs + inc - v;
    if (tid == 0) row_start[N_] = E_;
}

// ---------------- pass C: intra-block scan; also cursor = row_start -------
__global__ __launch_bounds__(256) void scan_write_kernel(const int* __restrict__ deg,
                                                         const int* __restrict__ blockOffs,
                                                         int* __restrict__ row_start,
                                                         int* __restrict__ cursor,
                                                         float* __restrict__ inv_deg,
                                                         int N_) {
    int tid = threadIdx.x;
    int i = blockIdx.x * 256 + tid;
    int v = (i < N_) ? deg[i] : 0;
    int lane = tid & 63, wid = tid >> 6;
    int inc = v;
#pragma unroll
    for (int off = 1; off < 64; off <<= 1) {
        int n = __shfl_up(inc, off, 64);
        if (lane >= off) inc += n;
    }
    __shared__ int ws[4];
    if (lane == 63) ws[wid] = inc;
    __syncthreads();
    int wofs = 0;
    for (int w = 0; w < wid; ++w) wofs += ws[w];
    if (i < N_) {
        int rs = blockOffs[blockIdx.x] + wofs + inc - v;
        row_start[i] = rs;
        cursor[i] = rs;
        inv_deg[i] = 1.0f / (float)(v > 0 ? v : 1);
    }
}

// ---------------- CSR placement: cursor pre-seeded with row_start ---------
__global__ void place_kernel(const int* __restrict__ src, const int* __restrict__ dst,
                             int* __restrict__ cursor, int* __restrict__ csr_src, int E_) {
    int e = blockIdx.x * blockDim.x + threadIdx.x;
    if (e >= E_) return;
    int pos = atomicAdd(&cursor[dst[e]], 1);
    csr_src[pos] = src[e];
}

// ---------------- x (f32) -> bf16 -----------------------------------------
__global__ __launch_bounds__(256) void cvt_bf16_kernel(const float* __restrict__ in,
                                                       unsigned short* __restrict__ out,
                                                       int n4) {
    int i = blockIdx.x * blockDim.x + threadIdx.x;
    if (i >= n4) return;
    float4 v = reinterpret_cast<const float4*>(in)[i];
    ushort4 o;
    o.x = f2bf(v.x); o.y = f2bf(v.y); o.z = f2bf(v.z); o.w = f2bf(v.w);
    reinterpret_cast<ushort4*>(out)[i] = o;
}

// ---------------- W^T prep: WtB[col][k] bf16, k<128 Wl, k>=128 Wr ---------
__global__ __launch_bounds__(256) void wt_prep(const float* __restrict__ Wl,
                                               const float* __restrict__ Wr,
                                               unsigned short* __restrict__ WtB) {
    int idx = blockIdx.x * 256 + threadIdx.x;  // 0..4095
    int c = idx >> 5;
    int g = idx & 31;
    int k0 = g * 8;
    const float* Wsrc = (k0 < 128) ? (Wl + (size_t)k0 * D + c)
                                   : (Wr + (size_t)(k0 - 128) * D + c);
    float v[8];
#pragma unroll
    for (int i = 0; i < 8; ++i) v[i] = Wsrc[(size_t)i * D];
    uint4 o;
    o.x = (unsigned int)f2bf(v[0]) | ((unsigned int)f2bf(v[1]) << 16);
    o.y = (unsigned int)f2bf(v[2]) | ((unsigned int)f2bf(v[3]) << 16);
    o.z = (unsigned int)f2bf(v[4]) | ((unsigned int)f2bf(v[5]) << 16);
    o.w = (unsigned int)f2bf(v[6]) | ((unsigned int)f2bf(v[7]) << 16);
    *reinterpret_cast<uint4*>(WtB + (size_t)c * 256 + k0) = o;
}

// ---------------- gather-mean: quarter-wave per edge, unroll 4 ------------
// 16 lanes x 16B (uint4 = 8 bf16) cover one 256B row; 16 rows in flight/wave.
__global__ __launch_bounds__(256) void gather_mean_bf16(
    const unsigned short* __restrict__ hb, const int* __restrict__ row_start,
    const int* __restrict__ csr_src, const float* __restrict__ inv_deg,
    unsigned short* __restrict__ aggb, int N_) {
    int node = blockIdx.x * 4 + (threadIdx.x >> 6);
    int lane = threadIdx.x & 63;
    if (node >= N_) return;
    int beg = row_start[node];
    int end = row_start[node + 1];
    int q = lane >> 4;   // quarter 0..3: handles edges beg+q, beg+q+4, ...
    int t = lane & 15;   // covers cols 8t..8t+7

    const uint4* hb4 = reinterpret_cast<const uint4*>(hb);  // row = 16 uint4

    float acc[8];
#pragma unroll
    for (int i = 0; i < 8; ++i) acc[i] = 0.f;

#define ACC8(V)                                             \
    acc[0] += bf2f_lo(V.x); acc[1] += bf2f_hi(V.x);         \
    acc[2] += bf2f_lo(V.y); acc[3] += bf2f_hi(V.y);         \
    acc[4] += bf2f_lo(V.z); acc[5] += bf2f_hi(V.z);         \
    acc[6] += bf2f_lo(V.w); acc[7] += bf2f_hi(V.w);

    int e = beg + q;
    for (; e + 12 < end; e += 16) {
        int s0 = csr_src[e];
        int s1 = csr_src[e + 4];
        int s2 = csr_src[e + 8];
        int s3 = csr_src[e + 12];
        uint4 v0 = hb4[(size_t)s0 * 16 + t];
        uint4 v1 = hb4[(size_t)s1 * 16 + t];
        uint4 v2 = hb4[(size_t)s2 * 16 + t];
        uint4 v3 = hb4[(size_t)s3 * 16 + t];
        ACC8(v0); ACC8(v1); ACC8(v2); ACC8(v3);
    }
    for (; e < end; e += 4) {
        uint4 v0 = hb4[(size_t)csr_src[e] * 16 + t];
        ACC8(v0);
    }
#undef ACC8

    // cross-quarter reduce: lanes {t, t+16, t+32, t+48} hold partial sums
#pragma unroll
    for (int i = 0; i < 8; ++i) {
        acc[i] += __shfl_xor(acc[i], 16, 64);
        acc[i] += __shfl_xor(acc[i], 32, 64);
    }
    if (q == 0) {
        float sc = inv_deg[node];
        uint4 o;
        o.x = (unsigned int)f2bf(acc[0] * sc) | ((unsigned int)f2bf(acc[1] * sc) << 16);
        o.y = (unsigned int)f2bf(acc[2] * sc) | ((unsigned int)f2bf(acc[3] * sc) << 16);
        o.z = (unsigned int)f2bf(acc[4] * sc) | ((unsigned int)f2bf(acc[5] * sc) << 16);
        o.w = (unsigned int)f2bf(acc[6] * sc) | ((unsigned int)f2bf(acc[7] * sc) << 16);
        reinterpret_cast<uint4*>(aggb + (size_t)node * D)[t] = o;
    }
}

// ---------------- fused MFMA GEMM: out = [agg|h] @ WtB^T + b --------------
// 512 thr = 8 waves, BM=128 (16 rows/wave), N=128 cols, K=256.
// WtB pre-converted bf16 [col][k]; staged to LDS via pure 16B copies.
// MODE 0: bf16 out + relu; MODE 1: f32 out, no relu.
template <int MODE>
__global__ __launch_bounds__(512) void sage_gemm_mfma(
    const unsigned short* __restrict__ hinb, const unsigned short* __restrict__ aggb,
    const unsigned short* __restrict__ WtB, const float* __restrict__ bias,
    void* __restrict__ out, int N_) {
    __shared__ unsigned short sWt[128][264];  // [col][k 0..255], +8 pad

    const int tid = threadIdx.x;
    for (int idx = tid; idx < 128 * 32; idx += 512) {
        int c = idx >> 5, g = idx & 31;
        *reinterpret_cast<uint4*>(&sWt[c][g * 8]) =
            reinterpret_cast<const uint4*>(WtB + (size_t)c * 256)[g];
    }
    __syncthreads();

    const int lane = tid & 63;
    const int w = tid >> 6;       // 0..7
    const int q = lane >> 4;      // 0..3
    const int c = lane & 15;      // 0..15
    const int R = blockIdx.x * 128 + w * 16;

    int r0 = R + c;  if (r0 > N_ - 1) r0 = N_ - 1;

    f32x4 acc[8];
#pragma unroll
    for (int n = 0; n < 8; ++n) acc[n] = (f32x4){0.f, 0.f, 0.f, 0.f};

#pragma unroll
    for (int ks = 0; ks < 8; ++ks) {
        int kg = ks * 32 + q * 8;
        const unsigned short* base = (kg < 128) ? (aggb + kg) : (hinb + (kg - 128));
        bf16x8 a0 = *reinterpret_cast<const bf16x8*>(base + (size_t)r0 * D);
#pragma unroll
        for (int n = 0; n < 8; ++n) {
            bf16x8 b = *reinterpret_cast<const bf16x8*>(&sWt[n * 16 + c][ks * 32 + q * 8]);
            acc[n] = __builtin_amdgcn_mfma_f32_16x16x32_bf16(a0, b, acc[n], 0, 0, 0);
        }
    }

    // epilogue: C row=(q*4+r), col=c within each 16x16 frag  [m89-verified]
    unsigned short* outb = (unsigned short*)out;
    float* outf = (float*)out;
#pragma unroll
    for (int n = 0; n < 8; ++n) {
        int col = n * 16 + c;
        float bv = bias[col];
#pragma unroll
        for (int r = 0; r < 4; ++r) {
            int row = R + q * 4 + r;
            if (row < N_) {
                float v = acc[n][r] + bv;
                if (MODE == 0) {
                    v = fmaxf(v, 0.f);
                    outb[(size_t)row * D + col] = f2bf(v);
                } else {
                    outf[(size_t)row * D + col] = v;
                }
            }
        }
    }
}

extern "C" void kernel_launch(void* const* d_in, const int* in_sizes, int n_in,
                              void* d_out, int out_size, void* d_ws, size_t ws_size,
                              hipStream_t stream) {
    const float* x = (const float*)d_in[0];
    const int* edge = (const int*)d_in[1];
    const float* Wl[3] = {(const float*)d_in[2], (const float*)d_in[5], (const float*)d_in[8]};
    const float* Wr[3] = {(const float*)d_in[3], (const float*)d_in[6], (const float*)d_in[9]};
    const float* bs[3] = {(const float*)d_in[4], (const float*)d_in[7], (const float*)d_in[10]};

    const int N_ = in_sizes[0] / D;
    const int E_ = in_sizes[1] / 2;
    const int* src = edge;
    const int* dst = edge + E_;

    char* ws = (char*)d_ws;
    size_t bmat = (size_t)N_ * D * sizeof(unsigned short);  // 10.24 MB
    unsigned short* xb = (unsigned short*)ws;                // also reused as h2b
    unsigned short* h1b = (unsigned short*)(ws + bmat);
    unsigned short* aggb = (unsigned short*)(ws + 2 * bmat);
    char* p = ws + 3 * bmat;
    int* deg_i = (int*)p;       p += (size_t)N_ * 4;
    int* row_start = (int*)p;   p += (size_t)(N_ + 1) * 4;
    int* cursor = (int*)p;      p += (size_t)N_ * 4;
    float* inv_deg = (float*)p; p += (size_t)N_ * 4;
    int* blockSums = (int*)p;   p += 1024;
    int* blockOffs = (int*)p;   p += 1024;
    unsigned short* WtB = (unsigned short*)p; p += 3 * 128 * 256 * sizeof(unsigned short);
    int* csr_src = (int*)p;     p += (size_t)E_ * 4;

    const int nb = (N_ + 255) / 256;  // 157 <= 256

    // ---- CSR build (once; reused by all 3 layers) ----
    hipMemsetAsync(deg_i, 0, (size_t)N_ * sizeof(int), stream);
    deg_count_kernel<<<(E_ + 255) / 256, 256, 0, stream>>>(dst, deg_i, E_);
    block_sum_kernel<<<nb, 256, 0, stream>>>(deg_i, blockSums, N_);
    scan_sums_kernel<<<1, 256, 0, stream>>>(blockSums, blockOffs, nb, row_start, N_, E_);
    scan_write_kernel<<<nb, 256, 0, stream>>>(deg_i, blockOffs, row_start, cursor, inv_deg, N_);
    place_kernel<<<(E_ + 255) / 256, 256, 0, stream>>>(src, dst, cursor, csr_src, E_);

    // weight prep (all 3 layers) + x -> bf16
    for (int l = 0; l < 3; ++l)
        wt_prep<<<16, 256, 0, stream>>>(Wl[l], Wr[l], WtB + (size_t)l * 128 * 256);
    int n4 = N_ * D / 4;
    cvt_bf16_kernel<<<(n4 + 255) / 256, 256, 0, stream>>>(x, xb, n4);

    int gemm_blocks = (N_ + 127) / 128;
    unsigned short* h2b = xb;  // x dead after layer 0

    // layer 0
    gather_mean_bf16<<<(N_ + 3) / 4, 256, 0, stream>>>(xb, row_start, csr_src, inv_deg, aggb, N_);
    sage_gemm_mfma<0><<<gemm_blocks, 512, 0, stream>>>(xb, aggb, WtB, bs[0], h1b, N_);
    // layer 1
    gather_mean_bf16<<<(N_ + 3) / 4, 256, 0, stream>>>(h1b, row_start, csr_src, inv_deg, aggb, N_);
    sage_gemm_mfma<0><<<gemm_blocks, 512, 0, stream>>>(h1b, aggb, WtB + 128 * 256, bs[1], h2b, N_);
    // layer 2
    gather_mean_bf16<<<(N_ + 3) / 4, 256, 0, stream>>>(h2b, row_start, csr_src, inv_deg, aggb, N_);
    sage_gemm_mfma<1><<<gemm_blocks, 512, 0, stream>>>(h2b, aggb, WtB + 2 * 128 * 256, bs[2], d_out, N_);
}